// Round 2
// baseline (662.264 us; speedup 1.0000x reference)
//
#include <hip/hip_runtime.h>
#include <hip/hip_bf16.h>
#include <hip/hip_fp16.h>

// NEZHA-style MHA: B=4, S=1024, H=12, DK=DV=64, DM=768
#define NS 1024
#define NB 4
#define NH 12
#define NDM 768
#define NBH 48   // NB*NH

typedef __attribute__((ext_vector_type(8))) short bf16x8;
typedef __attribute__((ext_vector_type(4))) float f32x4;

__device__ __forceinline__ ushort f2b(float f){            // f32 -> bf16 (RNE)
  uint u = __float_as_uint(f);
  u += 0x7fffu + ((u >> 16) & 1u);
  return (ushort)(u >> 16);
}
__device__ __forceinline__ float b2f(ushort s){ return __uint_as_float(((uint)s) << 16); }
__device__ __forceinline__ ushort f2h(float f){
  __half h = __float2half(f); ushort u; __builtin_memcpy(&u, &h, 2); return u;
}
__device__ __forceinline__ float h2f(ushort u){
  __half h; __builtin_memcpy(&h, &u, 2); return __half2float(h);
}
__device__ __forceinline__ f32x4 mfma16(bf16x8 a, bf16x8 b, f32x4 c){
  return __builtin_amdgcn_mfma_f32_16x16x32_bf16(a, b, c, 0, 0, 0);
}

// ---------------- K1: fp32 -> bf16 convert (vectorized) ----------------
__global__ void k_cvt(const float* __restrict__ src, ushort* __restrict__ dst, int n){
  int i = (blockIdx.x * blockDim.x + threadIdx.x) * 4;
  if (i >= n) return;
  float4 v = *(const float4*)(src + i);
  ushort4 o; o.x = f2b(v.x); o.y = f2b(v.y); o.z = f2b(v.z); o.w = f2b(v.w);
  *(ushort4*)(dst + i) = o;
}

// ---------------- K1b: W (m,n) fp32 -> WT (n,m) bf16, scaled ----------------
__global__ void k_wT(const float* __restrict__ W, ushort* __restrict__ WT, float scale){
  __shared__ float tl[32][33];
  int bx = blockIdx.x * 32, by = blockIdx.y * 32;
  int tx = threadIdx.x, ty = threadIdx.y;
  #pragma unroll
  for (int r = 0; r < 32; r += 8) tl[ty + r][tx] = W[(by + ty + r) * NDM + bx + tx];
  __syncthreads();
  #pragma unroll
  for (int r = 0; r < 32; r += 8) WT[(bx + ty + r) * NDM + by + tx] = f2b(tl[tx][ty + r] * scale);
}

// ------- K2/K6: GEMM  M x 768 x 768.  A: MxK k-contig bf16, Bt: NxK k-contig bf16 -------
template<int OUT_F32>
__global__ __launch_bounds__(256) void k_gemm768(const ushort* __restrict__ A,
    const ushort* __restrict__ Bt, const float* __restrict__ bias, float bscale,
    void* __restrict__ out){
  __shared__ ushort As[128][72];
  __shared__ ushort Bs[128][72];
  int m0 = blockIdx.x * 128, n0 = blockIdx.y * 128;
  int t = threadIdx.x, w = t >> 6, l = t & 63;
  int wm = (w >> 1) * 64, wn = (w & 1) * 64;
  f32x4 acc[4][4] = {};
  for (int k0 = 0; k0 < 768; k0 += 64){
    __syncthreads();
    #pragma unroll
    for (int it = 0; it < 4; ++it){
      int idx = it * 256 + t, r = idx >> 3, c = (idx & 7) * 8;
      *(bf16x8*)&As[r][c] = *(const bf16x8*)(A + (size_t)(m0 + r) * NDM + k0 + c);
      *(bf16x8*)&Bs[r][c] = *(const bf16x8*)(Bt + (size_t)(n0 + r) * NDM + k0 + c);
    }
    __syncthreads();
    #pragma unroll
    for (int ks = 0; ks < 2; ++ks){
      bf16x8 af[4], bfm[4];
      #pragma unroll
      for (int mt = 0; mt < 4; ++mt) af[mt] = *(const bf16x8*)&As[wm + mt*16 + (l & 15)][ks*32 + (l >> 4) * 8];
      #pragma unroll
      for (int nt = 0; nt < 4; ++nt) bfm[nt] = *(const bf16x8*)&Bs[wn + nt*16 + (l & 15)][ks*32 + (l >> 4) * 8];
      #pragma unroll
      for (int mt = 0; mt < 4; ++mt)
        #pragma unroll
        for (int nt = 0; nt < 4; ++nt)
          acc[mt][nt] = mfma16(af[mt], bfm[nt], acc[mt][nt]);
    }
  }
  #pragma unroll
  for (int mt = 0; mt < 4; ++mt)
    #pragma unroll
    for (int nt = 0; nt < 4; ++nt){
      int col = n0 + wn + nt * 16 + (l & 15);
      float bv = bias[col] * bscale;
      #pragma unroll
      for (int i = 0; i < 4; ++i){
        int row = m0 + wm + mt * 16 + (l >> 4) * 4 + i;
        float vv = acc[mt][nt][i] + bv;
        if (OUT_F32) ((float*)out)[(size_t)row * NDM + col] = vv;
        else ((ushort*)out)[(size_t)row * NDM + col] = f2b(vv);
      }
    }
}

// ---------------- K2b: vw (b,s,h,d) -> vwT (b,h,d,s) ----------------
__global__ void k_vT(const ushort* __restrict__ vw, ushort* __restrict__ vwT){
  __shared__ ushort tl[64][72];
  int s0 = blockIdx.x * 64, bh = blockIdx.y;
  int b = bh / NH, h = bh % NH;
  int t = threadIdx.x;
  #pragma unroll
  for (int it = 0; it < 2; ++it){
    int idx = it * 256 + t, r = idx >> 3, c = (idx & 7) * 8;
    *(bf16x8*)&tl[r][c] = *(const bf16x8*)(vw + ((size_t)(b * NS) + s0 + r) * NDM + h * 64 + c);
  }
  __syncthreads();
  #pragma unroll
  for (int it = 0; it < 16; ++it){
    int idx = it * 256 + t, d = idx >> 6, s = idx & 63;
    vwT[((size_t)bh * 64 + d) * NS + s0 + s] = tl[s][d];
  }
}

// ---------------- K3: S_qk[bh,j,k] = qw'[b,j,h,:] . kw[b,k,h,:]  (bf16 out) ----------------
__global__ __launch_bounds__(256) void k_qk(const ushort* __restrict__ qwp,
    const ushort* __restrict__ kwp, ushort* __restrict__ Sqk){
  __shared__ ushort As[128][72];
  __shared__ ushort Bs[128][72];
  int j0 = blockIdx.x * 128, k0 = blockIdx.y * 128, bh = blockIdx.z;
  int b = bh / NH, h = bh % NH;
  int t = threadIdx.x, w = t >> 6, l = t & 63;
  int wm = (w >> 1) * 64, wn = (w & 1) * 64;
  #pragma unroll
  for (int it = 0; it < 4; ++it){
    int idx = it * 256 + t, r = idx >> 3, c = (idx & 7) * 8;
    *(bf16x8*)&As[r][c] = *(const bf16x8*)(qwp + ((size_t)(b * NS) + j0 + r) * NDM + h * 64 + c);
    *(bf16x8*)&Bs[r][c] = *(const bf16x8*)(kwp + ((size_t)(b * NS) + k0 + r) * NDM + h * 64 + c);
  }
  __syncthreads();
  f32x4 acc[4][4] = {};
  #pragma unroll
  for (int ks = 0; ks < 2; ++ks){
    bf16x8 af[4], bfm[4];
    #pragma unroll
    for (int mt = 0; mt < 4; ++mt) af[mt] = *(const bf16x8*)&As[wm + mt*16 + (l & 15)][ks*32 + (l >> 4) * 8];
    #pragma unroll
    for (int nt = 0; nt < 4; ++nt) bfm[nt] = *(const bf16x8*)&Bs[wn + nt*16 + (l & 15)][ks*32 + (l >> 4) * 8];
    #pragma unroll
    for (int mt = 0; mt < 4; ++mt)
      #pragma unroll
      for (int nt = 0; nt < 4; ++nt)
        acc[mt][nt] = mfma16(af[mt], bfm[nt], acc[mt][nt]);
  }
  #pragma unroll
  for (int mt = 0; mt < 4; ++mt)
    #pragma unroll
    for (int nt = 0; nt < 4; ++nt)
      #pragma unroll
      for (int i = 0; i < 4; ++i){
        int jj = j0 + wm + mt * 16 + (l >> 4) * 4 + i;
        int kk = k0 + wn + nt * 16 + (l & 15);
        Sqk[((size_t)bh * NS + jj) * NS + kk] = f2b(acc[mt][nt][i]);
      }
}

// ---------------- K4: per-j mega kernel ----------------
// For query row j: S = S_qk + qw48 @ pb[j]^T (+amask, v_mask NEG) -> softmax -> A
// (written in-place over Sqk) -> out_pb[j,bh,d] = A48 @ pb[j].
// 8 waves. LDS: SA 48x1032 (f16 S, then bf16 A), PBs 256x72 (phase1) / 64x264 (phase3), QWs 48x72.
__global__ __launch_bounds__(512) void k_attnrow(const ushort* __restrict__ qw,
    ushort* __restrict__ SqkA, const float* __restrict__ pb,
    const float* __restrict__ amask, const int* __restrict__ vmask,
    float* __restrict__ outpb){
  __shared__ ushort SA[48][1032];
  __shared__ ushort PBs[18432];
  __shared__ ushort QWs[48][72];
  int j = blockIdx.x;
  int t = threadIdx.x, w = t >> 6, l = t & 63;
  if (t < 384){
    int bh = t >> 3, c = (t & 7) * 8;
    int b = bh / NH, h = bh % NH;
    *(bf16x8*)&QWs[bh][c] = *(const bf16x8*)(qw + ((size_t)(b * NS) + j) * NDM + h * 64 + c);
  }
  // ---- phase 1: scores ----
  for (int kc = 0; kc < 4; ++kc){
    __syncthreads();
    #pragma unroll
    for (int it = 0; it < 8; ++it){
      int idx = it * 512 + t;
      int kk = idx >> 4, c4 = (idx & 15) * 4;
      float4 pv = *(const float4*)(pb + ((size_t)j * NS + kc * 256 + kk) * 64 + c4);
      ushort4 o; o.x = f2b(pv.x); o.y = f2b(pv.y); o.z = f2b(pv.z); o.w = f2b(pv.w);
      *(ushort4*)&PBs[kk * 72 + c4] = o;
    }
    __syncthreads();
    f32x4 acc[3][2] = {};
    #pragma unroll
    for (int ks = 0; ks < 2; ++ks){
      bf16x8 af[3], bfm[2];
      #pragma unroll
      for (int mt = 0; mt < 3; ++mt) af[mt] = *(const bf16x8*)&QWs[mt*16 + (l & 15)][ks*32 + (l >> 4) * 8];
      #pragma unroll
      for (int nt = 0; nt < 2; ++nt) bfm[nt] = *(const bf16x8*)&PBs[(w*32 + nt*16 + (l & 15)) * 72 + ks*32 + (l >> 4) * 8];
      #pragma unroll
      for (int mt = 0; mt < 3; ++mt)
        #pragma unroll
        for (int nt = 0; nt < 2; ++nt)
          acc[mt][nt] = mfma16(af[mt], bfm[nt], acc[mt][nt]);
    }
    #pragma unroll
    for (int nt = 0; nt < 2; ++nt){
      int kg = kc * 256 + w * 32 + nt * 16 + (l & 15);
      float am = amask[j * NS + kg];
      #pragma unroll
      for (int mt = 0; mt < 3; ++mt)
        #pragma unroll
        for (int i = 0; i < 4; ++i){
          int bh = mt * 16 + (l >> 4) * 4 + i;
          int b = bh / NH;
          float sv = acc[mt][nt][i] + b2f(SqkA[((size_t)bh * NS + j) * NS + kg]) + am;
          sv = vmask[b * NS + kg] ? sv : -60000.0f;   // underflows to 0 after exp, like NEG
          SA[bh][kg] = f2h(sv);
        }
    }
  }
  __syncthreads();
  // ---- phase 2: softmax, 6 rows per wave ----
  for (int r = 0; r < 6; ++r){
    int bh = w * 6 + r;
    uint raw[8]; float sv[16];
    #pragma unroll
    for (int rr = 0; rr < 8; ++rr) raw[rr] = *(const uint*)&SA[bh][rr * 128 + l * 2];
    #pragma unroll
    for (int rr = 0; rr < 8; ++rr){
      sv[rr*2]   = h2f((ushort)(raw[rr] & 0xffffu));
      sv[rr*2+1] = h2f((ushort)(raw[rr] >> 16));
    }
    float mx = -1e30f;
    #pragma unroll
    for (int ii = 0; ii < 16; ++ii) mx = fmaxf(mx, sv[ii]);
    #pragma unroll
    for (int off = 32; off > 0; off >>= 1) mx = fmaxf(mx, __shfl_xor(mx, off));
    float p[16], sum = 0.f;
    #pragma unroll
    for (int ii = 0; ii < 16; ++ii){ p[ii] = __expf(sv[ii] - mx); sum += p[ii]; }
    #pragma unroll
    for (int off = 32; off > 0; off >>= 1) sum += __shfl_xor(sum, off);
    float inv = 1.0f / sum;
    size_t gbase = ((size_t)bh * NS + j) * NS;
    #pragma unroll
    for (int rr = 0; rr < 8; ++rr){
      uint pk = (uint)f2b(p[rr*2] * inv) | ((uint)f2b(p[rr*2+1] * inv) << 16);
      *(uint*)&SA[bh][rr * 128 + l * 2] = pk;                 // A (bf16) for phase 3
      *(uint*)((ushort*)SqkA + gbase + rr * 128 + l * 2) = pk; // A to global (aliases Sqk row j)
    }
  }
  // ---- phase 3: out_pb = A48 @ pb[j] ----
  f32x4 opb[2] = {};
  int ntl = (w < 4) ? 2 : 1;
  for (int kc = 0; kc < 4; ++kc){
    __syncthreads();
    for (int it = 0; it < 32; ++it){
      int idx = it * 512 + t;
      int kk = idx >> 6, d = idx & 63;
      PBs[d * 264 + kk] = f2b(pb[((size_t)j * NS + kc * 256 + kk) * 64 + d]);  // transposed stage
    }
    __syncthreads();
    for (int tt = 0; tt < ntl; ++tt){
      int tau = w + tt * 8, mt = tau >> 2, nt = tau & 3;
      #pragma unroll
      for (int ks = 0; ks < 8; ++ks){
        bf16x8 af  = *(const bf16x8*)&SA[mt*16 + (l & 15)][kc*256 + ks*32 + (l >> 4) * 8];
        bf16x8 bfm = *(const bf16x8*)&PBs[(nt*16 + (l & 15)) * 264 + ks*32 + (l >> 4) * 8];
        opb[tt] = mfma16(af, bfm, opb[tt]);
      }
    }
  }
  for (int tt = 0; tt < ntl; ++tt){
    int tau = w + tt * 8, mt = tau >> 2, nt = tau & 3;
    #pragma unroll
    for (int i = 0; i < 4; ++i){
      int bh = mt * 16 + (l >> 4) * 4 + i, d = nt * 16 + (l & 15);
      outpb[((size_t)j * NBH + bh) * 64 + d] = opb[tt][i];
    }
  }
}

// ---------------- K5: attn[b,j,h*64+d] = A[bh,j,:] @ vwT[bh,d,:] + out_pb[j,bh,d] ----------------
__global__ __launch_bounds__(256) void k_pv(const ushort* __restrict__ Abuf,
    const ushort* __restrict__ vwT, const float* __restrict__ outpb,
    ushort* __restrict__ attn){
  __shared__ ushort As[128][72];
  __shared__ ushort Bs[64][72];
  int j0 = blockIdx.x * 128, bh = blockIdx.y;
  int b = bh / NH, h = bh % NH;
  int t = threadIdx.x, w = t >> 6, l = t & 63;
  f32x4 acc[2][4] = {};
  for (int k0 = 0; k0 < NS; k0 += 64){
    __syncthreads();
    #pragma unroll
    for (int it = 0; it < 4; ++it){
      int idx = it * 256 + t, r = idx >> 3, c = (idx & 7) * 8;
      *(bf16x8*)&As[r][c] = *(const bf16x8*)(Abuf + ((size_t)bh * NS + j0 + r) * NS + k0 + c);
    }
    #pragma unroll
    for (int it = 0; it < 2; ++it){
      int idx = it * 256 + t, r = idx >> 3, c = (idx & 7) * 8;
      *(bf16x8*)&Bs[r][c] = *(const bf16x8*)(vwT + ((size_t)bh * 64 + r) * NS + k0 + c);
    }
    __syncthreads();
    #pragma unroll
    for (int ks = 0; ks < 2; ++ks){
      bf16x8 af[2], bfm[4];
      #pragma unroll
      for (int mt = 0; mt < 2; ++mt) af[mt] = *(const bf16x8*)&As[w*32 + mt*16 + (l & 15)][ks*32 + (l >> 4) * 8];
      #pragma unroll
      for (int nt = 0; nt < 4; ++nt) bfm[nt] = *(const bf16x8*)&Bs[nt*16 + (l & 15)][ks*32 + (l >> 4) * 8];
      #pragma unroll
      for (int mt = 0; mt < 2; ++mt)
        #pragma unroll
        for (int nt = 0; nt < 4; ++nt)
          acc[mt][nt] = mfma16(af[mt], bfm[nt], acc[mt][nt]);
    }
  }
  #pragma unroll
  for (int mt = 0; mt < 2; ++mt)
    #pragma unroll
    for (int nt = 0; nt < 4; ++nt)
      #pragma unroll
      for (int i = 0; i < 4; ++i){
        int jj = j0 + w * 32 + mt * 16 + (l >> 4) * 4 + i;
        int d = nt * 16 + (l & 15);
        float vv = acc[mt][nt][i] + outpb[((size_t)jj * NBH + bh) * 64 + d];
        attn[((size_t)(b * NS) + jj) * NDM + h * 64 + d] = f2b(vv);
      }
}

extern "C" void kernel_launch(void* const* d_in, const int* in_sizes, int n_in,
                              void* d_out, int out_size, void* d_ws, size_t ws_size,
                              hipStream_t stream) {
  const float* q     = (const float*)d_in[0];
  const float* k     = (const float*)d_in[1];
  const float* v     = (const float*)d_in[2];
  const float* amask = (const float*)d_in[3];
  const float* pb    = (const float*)d_in[4];
  const int*   vmask = (const int*)d_in[5];
  const float* Wq    = (const float*)d_in[6];
  const float* bq    = (const float*)d_in[7];
  const float* Wk    = (const float*)d_in[8];
  const float* bk    = (const float*)d_in[9];
  const float* Wv    = (const float*)d_in[10];
  const float* bv    = (const float*)d_in[11];
  const float* Wo    = (const float*)d_in[12];
  const float* bo    = (const float*)d_in[13];
  float* out = (float*)d_out;

  char* ws = (char*)d_ws;
  const size_t SZ_T  = (size_t)NB * NS * NDM * 2;     // 6291456 (bf16 tensor)
  const size_t SZ_WT = (size_t)NDM * NDM * 2;         // 1179648
  const size_t SZ_S  = (size_t)NBH * NS * NS * 2;     // 100663296
  size_t off = 0;
  ushort* qbf  = (ushort*)(ws + off); off += SZ_T;    // dead after q-projection -> attn aliases it
  ushort* kbf  = (ushort*)(ws + off); off += SZ_T;    // dead after k-projection -> vwT aliases it
  ushort* vbf  = (ushort*)(ws + off); off += SZ_T;
  ushort* WqT  = (ushort*)(ws + off); off += SZ_WT;
  ushort* WkT  = (ushort*)(ws + off); off += SZ_WT;
  ushort* WvT  = (ushort*)(ws + off); off += SZ_WT;
  ushort* WoT  = (ushort*)(ws + off); off += SZ_WT;
  ushort* qwp  = (ushort*)(ws + off); off += SZ_T;
  ushort* kwp  = (ushort*)(ws + off); off += SZ_T;
  ushort* vwp  = (ushort*)(ws + off); off += SZ_T;
  ushort* Sqk  = (ushort*)(ws + off); off += SZ_S;    // also holds A after K4
  float*  opb  = (float*)(ws + off);  off += (size_t)NS * NBH * 64 * 4;
  ushort* vwT  = kbf;                                 // alias (kbf dead before K2b)
  ushort* attn = qbf;                                 // alias (qbf dead before K5)

  const int nElem = NB * NS * NDM;                    // 3145728
  // K1: converts
  k_cvt<<<dim3(nElem / 1024), dim3(256), 0, stream>>>(q, qbf, nElem);
  k_cvt<<<dim3(nElem / 1024), dim3(256), 0, stream>>>(k, kbf, nElem);
  k_cvt<<<dim3(nElem / 1024), dim3(256), 0, stream>>>(v, vbf, nElem);
  k_wT<<<dim3(24, 24), dim3(32, 8), 0, stream>>>(Wq, WqT, 0.125f);   // fold 1/sqrt(DK)
  k_wT<<<dim3(24, 24), dim3(32, 8), 0, stream>>>(Wk, WkT, 1.0f);
  k_wT<<<dim3(24, 24), dim3(32, 8), 0, stream>>>(Wv, WvT, 1.0f);
  k_wT<<<dim3(24, 24), dim3(32, 8), 0, stream>>>(Wo, WoT, 1.0f);
  // K2: projections (qw prescaled by 1/8, incl. bias)
  k_gemm768<0><<<dim3(32, 6), dim3(256), 0, stream>>>(kbf, WkT, bk, 1.0f, kwp);   // kbf freed first
  k_gemm768<0><<<dim3(32, 6), dim3(256), 0, stream>>>(qbf, WqT, bq, 0.125f, qwp);
  k_gemm768<0><<<dim3(32, 6), dim3(256), 0, stream>>>(vbf, WvT, bv, 1.0f, vwp);
  // K2b: vw transpose (writes into kbf alias)
  k_vT<<<dim3(16, NBH), dim3(256), 0, stream>>>(vwp, vwT);
  // K3: QK^T
  k_qk<<<dim3(8, 8, NBH), dim3(256), 0, stream>>>(qwp, kwp, Sqk);
  // K4: per-j scores+softmax+out_pb
  k_attnrow<<<dim3(NS), dim3(512), 0, stream>>>(qwp, Sqk, pb, amask, vmask, opb);
  // K5: PV + out_pb add (writes into qbf alias)
  k_pv<<<dim3(8, NBH), dim3(256), 0, stream>>>(Sqk, vwT, opb, attn);
  // K6: output projection -> fp32
  k_gemm768<1><<<dim3(32, 6), dim3(256), 0, stream>>>(attn, WoT, bo, 1.0f, out);
}